// Round 5
// baseline (1248.553 us; speedup 1.0000x reference)
//
#include <hip/hip_runtime.h>

#define Hh 32
#define Ww 128
#define BB 32
#define CC 16
#define OO 128
#define SPIN_CAP (1 << 23)
#define FSTRIDE 32    // 32 ints = 128B per flag: one cache line per flag, no false sharing

typedef __attribute__((ext_vector_type(8))) short short8;
typedef __attribute__((ext_vector_type(4))) float f32x4;

__device__ inline short f2bf(float f) {
    unsigned u = __builtin_bit_cast(unsigned, f);
    unsigned r = (u + 0x7FFFu + ((u >> 16) & 1u)) >> 16;
    return (short)r;
}
__device__ inline float bf2f(short s) {
    unsigned u = ((unsigned)(unsigned short)s) << 16;
    return __builtin_bit_cast(float, u);
}
__device__ inline float rcp_(float x) { return __builtin_amdgcn_rcpf(x); }
__device__ inline float sigm(float x) {
    return rcp_(1.f + __builtin_amdgcn_exp2f(-1.442695041f * x));
}
__device__ inline float tanh_(float x) {
    return 1.f - 2.f * rcp_(__builtin_amdgcn_exp2f(2.885390082f * x) + 1.f);
}

__device__ inline unsigned long long aload64(const unsigned long long* p) {
    return __hip_atomic_load(p, __ATOMIC_RELAXED, __HIP_MEMORY_SCOPE_AGENT);
}
__device__ inline void astore64(unsigned long long* p, unsigned long long v) {
    __hip_atomic_store(p, v, __ATOMIC_RELAXED, __HIP_MEMORY_SCOPE_AGENT);
}
__device__ inline void astore16(short* p, short v) {
    __hip_atomic_store(p, v, __ATOMIC_RELAXED, __HIP_MEMORY_SCOPE_AGENT);
}
__device__ inline int aloadI(const int* p) {
    return __hip_atomic_load(p, __ATOMIC_RELAXED, __HIP_MEMORY_SCOPE_AGENT);
}
__device__ inline void astoreI(int* p, int v) {
    __hip_atomic_store(p, v, __ATOMIC_RELAXED, __HIP_MEMORY_SCOPE_AGENT);
}

// ---- init: zero padded flags, transpose x (B,C,H,W) fp32 -> xT (H,W,B,C) bf16 ----
__global__ void mdlstm_init(const float* __restrict__ x, short* __restrict__ xT,
                            int* __restrict__ flags) {
    int idx = blockIdx.x * 256 + threadIdx.x;
    if (blockIdx.x < 64) flags[idx] = 0;   // 2 regions * 256 flags * FSTRIDE ints = 16384
    int w = idx & 127;
    int h = (idx >> 7) & 31;
    int c = (idx >> 12) & 15;
    int b = idx >> 16;
    float v = x[idx];
    xT[((h * Ww + w) * BB + b) * CC + c] = f2bf(v);
}

// ---- main persistent wavefront kernel: 256 blocks x 512 threads, 1 block/CU ----
__global__ void __launch_bounds__(512, 1) mdlstm_main(
    const short* __restrict__ xT,
    const float* __restrict__ w_ii, const float* __restrict__ w_hi, const float* __restrict__ b_i,
    const float* __restrict__ w_if, const float* __restrict__ w_hf, const float* __restrict__ b_f,
    const float* __restrict__ w_ig, const float* __restrict__ w_hg, const float* __restrict__ b_g,
    const float* __restrict__ w_io, const float* __restrict__ w_ho, const float* __restrict__ b_o,
    const float* __restrict__ wsum, const float* __restrict__ bias,
    short* __restrict__ hring, float* __restrict__ cring,
    int* __restrict__ prog, int* __restrict__ cons,
    float* __restrict__ out, int depth)
{
    const int chain = blockIdx.x & 7;       // d*2+s -> one XCD per chain (ring stays in that L2)
    const int r     = blockIdx.x >> 3;      // scan row 0..31
    const int d     = chain >> 1;
    const int s     = chain & 1;
    const int b0    = s * 16;
    const bool fy   = (d >= 2);
    const bool fx   = (d & 1);
    const int hh    = fy ? (Hh - 1 - r) : r;

    const int tid  = threadIdx.x;
    const int wv   = tid >> 6;    // 0..7
    const int lane = tid & 63;
    const int lr   = lane & 15;
    const int lh   = lane >> 4;
    const int on   = wv * 16 + lr;

    // stage: element (o, w, b) -> stage[o*256 + ((w ^ ((o>>3)&15))<<4) + b]  (64 KB static)
    __shared__ short stage[OO * 256];

    // ---------- weight fragments (registers, loaded once) ----------
    const float* whp[4] = {w_hi, w_hf, w_hg, w_ho};
    const float* wip[4] = {w_ii, w_if, w_ig, w_io};
    short8 whf[4][4];
    short8 wif_[4];
#pragma unroll
    for (int g = 0; g < 4; ++g) {
#pragma unroll
        for (int kt = 0; kt < 4; ++kt) {
            const float* p = whp[g] + ((d * OO + on) * OO + kt * 32 + lh * 8);
            short8 f;
#pragma unroll
            for (int j = 0; j < 8; ++j) f[j] = f2bf(p[j]);
            whf[g][kt] = f;
        }
        short8 fi = (short8)(short)0;
        if (lh < 2) {
            const float* p = wip[g] + ((d * OO + on) * CC + lh * 8);
#pragma unroll
            for (int j = 0; j < 8; ++j) fi[j] = f2bf(p[j]);
        }
        wif_[g] = fi;
    }

    const float bi  = b_i[d * OO + on];
    const float bf_ = b_f[d * OO + on];
    const float bg_ = b_g[d * OO + on];
    const float bo_ = b_o[d * OO + on];
    const float bb_ = bias[d * OO + on];
    const float ws0 = wsum[d * 2 + 0];
    const float ws1 = wsum[d * 2 + 1];

    // flags: one 128B line each; value = columns complete (published at odd cols: 2,4,...)
    int* topf      = prog + ((d * 32 + (r - 1)) * 2 + s) * FSTRIDE;
    int* myprog    = prog + ((d * 32 + r) * 2 + s) * FSTRIDE;
    int* mycons    = cons + ((d * 32 + r) * 2 + s) * FSTRIDE;
    int* consnext  = cons + ((d * 32 + (r + 1)) * 2 + s) * FSTRIDE;

    // ring layouts (s-split: zero cache-line sharing between s=0/s=1 chains / XCDs):
    //   hring: [(row*2+s)][slot][b':16][o:128] bf16  -> consumer A-frag = ONE 8B load
    //   cring: [(row*2+s)][slot][o:128][b':16] fp32  -> 2x8B both sides
    const int rbh_me  = ((d * 32 + r)     * 2 + s) * depth * (16 * OO);
    const int rbh_top = ((d * 32 + (r-1)) * 2 + s) * depth * (16 * OO);
    const int rbc_me  = ((d * 32 + r)     * 2 + s) * depth * (OO * 16);
    const int rbc_top = ((d * 32 + (r-1)) * 2 + s) * depth * (OO * 16);
    const int smask   = depth - 1;

    short8 hLf[4];
#pragma unroll
    for (int kt = 0; kt < 4; ++kt) hLf[kt] = (short8)(short)0;
    float cL[4] = {0.f, 0.f, 0.f, 0.f};

    // odd-column prefetch registers (loaded at even column; one flag covers the pair)
    short8 hTfB[4];
#pragma unroll
    for (int kt = 0; kt < 4; ++kt) hTfB[kt] = (short8)(short)0;
    float cTB[4] = {0.f, 0.f, 0.f, 0.f};

    int top_seen = 0, cons_seen = 0;
    const f32x4 zacc = {0.f, 0.f, 0.f, 0.f};

#pragma unroll 2
    for (int wsc = 0; wsc < Ww; ++wsc) {
        const int ww    = fx ? (Ww - 1 - wsc) : wsc;
        const int slot  = wsc & smask;
        const int wslot = ww & 15;
        const bool evenc = ((wsc & 1) == 0);

        // x input fragment (nt load: single-use, don't pollute L2)
        short8 xf = (short8)(short)0;
        if (lh < 2) {
            const short8* p = (const short8*)(xT + ((hh * Ww + ww) * BB + b0 + lr) * CC + lh * 8);
            xf = __builtin_nontemporal_load(p);
        }

        // ---------- top dependency: wait+load BOTH columns at even col; reuse at odd ----------
        short8 hTf[4];
        float cT[4];
        if (r > 0) {
            if (evenc) {
                const int need = wsc + 2;   // pair (wsc, wsc+1) published
                if (top_seen < need) {
                    int spin = 0;
                    while (top_seen < need && spin < SPIN_CAP) {
                        int v = 0;
                        if (lane == 0) v = aloadI(topf);
                        v = __shfl(v, 0, 64);
                        if (v < need) { __builtin_amdgcn_s_sleep(1); ++spin; } else top_seen = v;
                    }
                }
                // even wsc -> slot even -> slot+1 never wraps
                const short* hb = hring + rbh_top + slot * (16 * OO) + lr * OO;
#pragma unroll
                for (int kt = 0; kt < 4; ++kt) {
                    union { unsigned long long q; short8 v8; } u, u2;
                    u.q = aload64((const unsigned long long*)(hb + kt * 32 + lh * 8));
                    (void)u2;
                    // 8B holds 4 bf16; need 8 -> two loads
                    union { unsigned long long q[2]; short8 v; } w;
                    w.q[0] = aload64((const unsigned long long*)(hb + kt * 32 + lh * 8));
                    w.q[1] = aload64((const unsigned long long*)(hb + kt * 32 + lh * 8 + 4));
                    hTf[kt] = w.v;
                }
                const short* hb2 = hb + 16 * OO;
#pragma unroll
                for (int kt = 0; kt < 4; ++kt) {
                    union { unsigned long long q[2]; short8 v; } w;
                    w.q[0] = aload64((const unsigned long long*)(hb2 + kt * 32 + lh * 8));
                    w.q[1] = aload64((const unsigned long long*)(hb2 + kt * 32 + lh * 8 + 4));
                    hTfB[kt] = w.v;
                }
                const unsigned long long* cp =
                    (const unsigned long long*)(cring + rbc_top + slot * (OO * 16) + on * 16 + lh * 4);
                union { unsigned long long q; float f[2]; } c01, c23;
                c01.q = aload64(cp);
                c23.q = aload64(cp + 1);
                cT[0] = c01.f[0]; cT[1] = c01.f[1]; cT[2] = c23.f[0]; cT[3] = c23.f[1];
                const unsigned long long* cpB =
                    (const unsigned long long*)(cring + rbc_top + (slot + 1) * (OO * 16) + on * 16 + lh * 4);
                c01.q = aload64(cpB);
                c23.q = aload64(cpB + 1);
                cTB[0] = c01.f[0]; cTB[1] = c01.f[1]; cTB[2] = c23.f[0]; cTB[3] = c23.f[1];
            } else {
#pragma unroll
                for (int kt = 0; kt < 4; ++kt) hTf[kt] = hTfB[kt];
#pragma unroll
                for (int j = 0; j < 4; ++j) cT[j] = cTB[j];
            }
        } else {
#pragma unroll
            for (int kt = 0; kt < 4; ++kt) hTf[kt] = (short8)(short)0;
#pragma unroll
            for (int j = 0; j < 4; ++j) cT[j] = 0.f;
        }

        // ---------- MFMAs: x-proj + left first (independent of top loads), then top ----------
        f32x4 ax[4], accL[4], accT[4];
#pragma unroll
        for (int g = 0; g < 4; ++g)
            ax[g] = __builtin_amdgcn_mfma_f32_16x16x32_bf16(xf, wif_[g], zacc, 0, 0, 0);
#pragma unroll
        for (int g = 0; g < 4; ++g) {
            f32x4 a = ax[g];
#pragma unroll
            for (int kt = 0; kt < 4; ++kt)
                a = __builtin_amdgcn_mfma_f32_16x16x32_bf16(hLf[kt], whf[g][kt], a, 0, 0, 0);
            accL[g] = a;
        }
#pragma unroll
        for (int g = 0; g < 4; ++g) {
            f32x4 a = ax[g];
#pragma unroll
            for (int kt = 0; kt < 4; ++kt)
                a = __builtin_amdgcn_mfma_f32_16x16x32_bf16(hTf[kt], whf[g][kt], a, 0, 0, 0);
            accT[g] = a;
        }

        // ---------- elementwise LSTM cell (D-layout: col=on, row b = lh*4+j) ----------
        float ctv[4];
        union { short sh[4]; unsigned long long q; } hpack;
#pragma unroll
        for (int j = 0; j < 4; ++j) {
            float iT = sigm(accT[0][j] + bi);
            float fT = sigm(accT[1][j] + bf_);
            float gT = tanh_(accT[2][j] + bg_);
            float oT = sigm(accT[3][j] + bo_);
            float c0 = fT * cT[j] + iT * gT;
            float h0 = oT * tanh_(c0);

            float iL = sigm(accL[0][j] + bi);
            float fL = sigm(accL[1][j] + bf_);
            float gL = tanh_(accL[2][j] + bg_);
            float oL = sigm(accL[3][j] + bo_);
            float c1 = fL * cL[j] + iL * gL;
            float h1 = oL * tanh_(c1);

            float ct = ws0 * c0 + ws1 * c1 + bb_;
            float ht = ws0 * h0 + ws1 * h1 + bb_;
            cL[j] = ct;
            ctv[j] = ct;
            hpack.sh[j] = f2bf(ht);
        }

        // stage write: one 8B LDS write, swizzled column group
        {
            const int g_on = (on >> 3) & 15;
            *(unsigned long long*)&stage[on * 256 + ((wslot ^ g_on) << 4) + lh * 4] = hpack.q;
        }

        // ---------- back-pressure (even cols only; slack = depth/2 - 1 chunks) ----------
        if (r < 31 && evenc && wsc >= depth) {
            const int need = wsc - (depth - 2);
            if (cons_seen < need) {
                int spin = 0;
                while (cons_seen < need && spin < SPIN_CAP) {
                    int v = 0;
                    if (lane == 0) v = aloadI(consnext);
                    v = __shfl(v, 0, 64);
                    if (v < need) { __builtin_amdgcn_s_sleep(1); ++spin; } else cons_seen = v;
                }
            }
        }

        // ---------- ring publish straight from cell registers ----------
        if (r < 31) {
            // h: [b'][o] -> 4 scalar 2B stores (16-lane groups coalesce to 32B)
            short* hp = hring + rbh_me + slot * (16 * OO) + on;
#pragma unroll
            for (int j = 0; j < 4; ++j)
                astore16(hp + (lh * 4 + j) * OO, hpack.sh[j]);
            union { float f[2]; unsigned long long q; } p01, p23;
            p01.f[0] = ctv[0]; p01.f[1] = ctv[1];
            p23.f[0] = ctv[2]; p23.f[1] = ctv[3];
            unsigned long long* cp =
                (unsigned long long*)(cring + rbc_me + slot * (OO * 16) + on * 16 + lh * 4);
            astore64(cp, p01.q);
            astore64(cp + 1, p23.q);
        }

        __syncthreads();   // drains all waves' ring stores (vmcnt) + stage visibility

        // flag out IMMEDIATELY after the barrier, odd cols only (chunk boundary)
        if (!evenc && tid == 0) {
            if (r < 31) astoreI(myprog, wsc + 1);
            if (r > 0)  astoreI(mycons, wsc + 1);
        }

        // opportunistic non-blocking probe for next chunk's flag (hides one RTT under rebuild)
        if (r > 0 && !evenc && wsc < Ww - 1) {
            int v = 0;
            if (lane == 0) v = aloadI(topf);
            v = __shfl(v, 0, 64);
            if (v > top_seen) top_seen = v;
        }

        // rebuild h_left A-frags from stage (conflict-free via wslot swizzle)
#pragma unroll
        for (int kt = 0; kt < 4; ++kt) {
            const int col = ((wslot ^ (kt * 4 + lh)) << 4) + lr;
            short8 f;
#pragma unroll
            for (int jj = 0; jj < 8; ++jj)
                f[jj] = stage[(kt * 32 + lh * 8 + jj) * 256 + col];
            hLf[kt] = f;
        }

        // output dump every 16 steps; NON-TEMPORAL stores: don't evict the rings from L2.
        // Second barrier only here (stage WAR).
        if ((wsc & 15) == 15) {
            const int wbase = ww & ~15;
            const int q  = tid & 3;
            const int r0 = tid >> 2;
#pragma unroll
            for (int i = 0; i < 16; ++i) {
                const int row = r0 + (i << 7);
                const int o = row >> 4;
                const int b = row & 15;
                const int go = (o >> 3) & 15;
                f32x4 v;
#pragma unroll
                for (int k = 0; k < 4; ++k)
                    v[k] = bf2f(stage[o * 256 + (((q * 4 + k) ^ go) << 4) + b]);
                float* op = out + ((size_t)((d * OO + o) * BB + b0 + b)) * (Hh * Ww)
                                + hh * Ww + wbase + q * 4;
                __builtin_nontemporal_store(v, (f32x4*)op);
            }
            __syncthreads();
        }
    }
}

extern "C" void kernel_launch(void* const* d_in, const int* in_sizes, int n_in,
                              void* d_out, int out_size, void* d_ws, size_t ws_size,
                              hipStream_t stream) {
    (void)in_sizes; (void)n_in; (void)out_size;

    const float* x     = (const float*)d_in[0];
    const float* w_ii  = (const float*)d_in[1];
    const float* w_hi  = (const float*)d_in[2];
    const float* b_i   = (const float*)d_in[3];
    const float* w_if  = (const float*)d_in[4];
    const float* w_hf  = (const float*)d_in[5];
    const float* b_f   = (const float*)d_in[6];
    const float* w_ig  = (const float*)d_in[7];
    const float* w_hg  = (const float*)d_in[8];
    const float* b_g   = (const float*)d_in[9];
    const float* w_io  = (const float*)d_in[10];
    const float* w_ho  = (const float*)d_in[11];
    const float* b_o   = (const float*)d_in[12];
    const float* wsum  = (const float*)d_in[13];
    const float* bias  = (const float*)d_in[14];
    float* outp        = (float*)d_out;

    char* ws = (char*)d_ws;
    int*   flags  = (int*)ws;                               // 16384 ints = 64 KB
    short* xTp    = (short*)(ws + (64u << 10));             // 4 MB
    const size_t off_h = (64u << 10) + (4u << 20);

    // adaptive ring depth: hring = depth MB, cring = 2*depth MB
    int depth = 8;
    const size_t need8 = off_h + ((size_t)8 << 20) + ((size_t)16 << 20) + (1u << 20);
    if (ws_size < need8) depth = 4;

    short* hringp = (short*)(ws + off_h);
    float* cringp = (float*)(ws + off_h + ((size_t)depth << 20));
    int*   progp  = flags;
    int*   consp  = flags + 256 * FSTRIDE;

    hipLaunchKernelGGL(mdlstm_init, dim3(8192), dim3(256), 0, stream, x, xTp, flags);

    mdlstm_main<<<dim3(256), dim3(512), 0, stream>>>(
        xTp,
        w_ii, w_hi, b_i,
        w_if, w_hf, b_f,
        w_ig, w_hg, b_g,
        w_io, w_ho, b_o,
        wsum, bias,
        hringp, cringp, progp, consp,
        outp, depth);
}

// Round 6
// 1090.951 us; speedup vs baseline: 1.1445x; 1.1445x over previous
//
#include <hip/hip_runtime.h>

#define Hh 32
#define Ww 128
#define BB 32
#define CC 16
#define OO 128
#define SPIN_CAP (1 << 23)
#define FSTRIDE 32    // 32 ints = 128B per flag: one cache line per flag, no false sharing

typedef __attribute__((ext_vector_type(8))) short short8;
typedef __attribute__((ext_vector_type(4))) float f32x4;

__device__ inline short f2bf(float f) {
    unsigned u = __builtin_bit_cast(unsigned, f);
    unsigned r = (u + 0x7FFFu + ((u >> 16) & 1u)) >> 16;
    return (short)r;
}
__device__ inline float bf2f(short s) {
    unsigned u = ((unsigned)(unsigned short)s) << 16;
    return __builtin_bit_cast(float, u);
}
__device__ inline float rcp_(float x) { return __builtin_amdgcn_rcpf(x); }
__device__ inline float sigm(float x) {
    return rcp_(1.f + __builtin_amdgcn_exp2f(-1.442695041f * x));
}
__device__ inline float tanh_(float x) {
    return 1.f - 2.f * rcp_(__builtin_amdgcn_exp2f(2.885390082f * x) + 1.f);
}

__device__ inline unsigned long long aload64(const unsigned long long* p) {
    return __hip_atomic_load(p, __ATOMIC_RELAXED, __HIP_MEMORY_SCOPE_AGENT);
}
__device__ inline void astore64(unsigned long long* p, unsigned long long v) {
    __hip_atomic_store(p, v, __ATOMIC_RELAXED, __HIP_MEMORY_SCOPE_AGENT);
}
__device__ inline void astore16(short* p, short v) {
    __hip_atomic_store(p, v, __ATOMIC_RELAXED, __HIP_MEMORY_SCOPE_AGENT);
}
__device__ inline int aloadI(const int* p) {
    return __hip_atomic_load(p, __ATOMIC_RELAXED, __HIP_MEMORY_SCOPE_AGENT);
}
__device__ inline void astoreI(int* p, int v) {
    __hip_atomic_store(p, v, __ATOMIC_RELAXED, __HIP_MEMORY_SCOPE_AGENT);
}

// ---- init: zero padded flags, transpose x (B,C,H,W) fp32 -> xT (H,W,B,C) bf16 ----
__global__ void mdlstm_init(const float* __restrict__ x, short* __restrict__ xT,
                            int* __restrict__ flags) {
    int idx = blockIdx.x * 256 + threadIdx.x;
    if (blockIdx.x < 64) flags[idx] = 0;   // 2 regions * 256 flags * FSTRIDE ints = 16384
    int w = idx & 127;
    int h = (idx >> 7) & 31;
    int c = (idx >> 12) & 15;
    int b = idx >> 16;
    float v = x[idx];
    xT[((h * Ww + w) * BB + b) * CC + c] = f2bf(v);
}

// ---- main persistent wavefront kernel: 256 blocks x 512 threads, 1 block/CU ----
__global__ void __launch_bounds__(512, 1) mdlstm_main(
    const short* __restrict__ xT,
    const float* __restrict__ w_ii, const float* __restrict__ w_hi, const float* __restrict__ b_i,
    const float* __restrict__ w_if, const float* __restrict__ w_hf, const float* __restrict__ b_f,
    const float* __restrict__ w_ig, const float* __restrict__ w_hg, const float* __restrict__ b_g,
    const float* __restrict__ w_io, const float* __restrict__ w_ho, const float* __restrict__ b_o,
    const float* __restrict__ wsum, const float* __restrict__ bias,
    short* __restrict__ hring, float* __restrict__ cring,
    int* __restrict__ prog, int* __restrict__ cons,
    float* __restrict__ out, int depth)
{
    const int chain = blockIdx.x & 7;       // d*2+s -> one XCD per chain (ring stays in that L2)
    const int r     = blockIdx.x >> 3;      // scan row 0..31
    const int d     = chain >> 1;
    const int s     = chain & 1;
    const int b0    = s * 16;
    const bool fy   = (d >= 2);
    const bool fx   = (d & 1);
    const int hh    = fy ? (Hh - 1 - r) : r;

    const int tid  = threadIdx.x;
    const int wv   = tid >> 6;    // 0..7
    const int lane = tid & 63;
    const int lr   = lane & 15;
    const int lh   = lane >> 4;
    const int on   = wv * 16 + lr;

    // stage: element (o, w, b) -> stage[o*256 + ((w ^ ((o>>3)&15))<<4) + b]  (64 KB static)
    __shared__ short stage[OO * 256];

    // ---------- weight fragments (registers, loaded once) ----------
    const float* whp[4] = {w_hi, w_hf, w_hg, w_ho};
    const float* wip[4] = {w_ii, w_if, w_ig, w_io};
    short8 whf[4][4];
    short8 wif_[4];
#pragma unroll
    for (int g = 0; g < 4; ++g) {
#pragma unroll
        for (int kt = 0; kt < 4; ++kt) {
            const float* p = whp[g] + ((d * OO + on) * OO + kt * 32 + lh * 8);
            short8 f;
#pragma unroll
            for (int j = 0; j < 8; ++j) f[j] = f2bf(p[j]);
            whf[g][kt] = f;
        }
        short8 fi = (short8)(short)0;
        if (lh < 2) {
            const float* p = wip[g] + ((d * OO + on) * CC + lh * 8);
#pragma unroll
            for (int j = 0; j < 8; ++j) fi[j] = f2bf(p[j]);
        }
        wif_[g] = fi;
    }

    const float bi  = b_i[d * OO + on];
    const float bf_ = b_f[d * OO + on];
    const float bg_ = b_g[d * OO + on];
    const float bo_ = b_o[d * OO + on];
    const float bb_ = bias[d * OO + on];
    const float ws0 = wsum[d * 2 + 0];
    const float ws1 = wsum[d * 2 + 1];

    // flags: one 128B line each; value = columns complete (published at odd cols: 2,4,...)
    int* topf      = prog + ((d * 32 + (r - 1)) * 2 + s) * FSTRIDE;
    int* myprog    = prog + ((d * 32 + r) * 2 + s) * FSTRIDE;
    int* mycons    = cons + ((d * 32 + r) * 2 + s) * FSTRIDE;
    int* consnext  = cons + ((d * 32 + (r + 1)) * 2 + s) * FSTRIDE;

    // ring layouts (s-split: zero cache-line sharing between s=0/s=1 chains / XCDs):
    //   hring: [(row*2+s)][slot][b':16][o:128] bf16  -> consumer A-frag = 2x8B vector loads
    //   cring: [(row*2+s)][slot][o:128][b':16] fp32  -> 2x8B both sides
    const int rbh_me  = ((d * 32 + r)     * 2 + s) * depth * (16 * OO);
    const int rbh_top = ((d * 32 + (r-1)) * 2 + s) * depth * (16 * OO);
    const int rbc_me  = ((d * 32 + r)     * 2 + s) * depth * (OO * 16);
    const int rbc_top = ((d * 32 + (r-1)) * 2 + s) * depth * (OO * 16);
    const int smask   = depth - 1;

    short8 hLf[4];
#pragma unroll
    for (int kt = 0; kt < 4; ++kt) hLf[kt] = (short8)(short)0;
    float cL[4] = {0.f, 0.f, 0.f, 0.f};

    // odd-column prefetch registers (loaded at even column; one flag covers the pair)
    short8 hTfB[4];
#pragma unroll
    for (int kt = 0; kt < 4; ++kt) hTfB[kt] = (short8)(short)0;
    float cTB[4] = {0.f, 0.f, 0.f, 0.f};

    int top_seen = 0, cons_seen = 0;
    const f32x4 zacc = {0.f, 0.f, 0.f, 0.f};

    // x fragment prefetch: load column 0 now; inside the loop prefetch wsc+1.
    short8 xf_next = (short8)(short)0;
    {
        const int ww0 = fx ? (Ww - 1) : 0;
        if (lh < 2)
            xf_next = *(const short8*)(xT + ((hh * Ww + ww0) * BB + b0 + lr) * CC + lh * 8);
    }

#pragma unroll 2
    for (int wsc = 0; wsc < Ww; ++wsc) {
        const int ww    = fx ? (Ww - 1 - wsc) : wsc;
        const int slot  = wsc & smask;
        const int wslot = ww & 15;
        const bool evenc = ((wsc & 1) == 0);

        const short8 xf = xf_next;

        // ---------- top dependency: wait+load BOTH columns at even col; reuse at odd ----------
        short8 hTf[4];
        float cT[4];
        if (r > 0) {
            if (evenc) {
                const int need = wsc + 2;   // pair (wsc, wsc+1) published
                if (top_seen < need) {
                    int spin = 0;
                    while (top_seen < need && spin < SPIN_CAP) {
                        const int v = aloadI(topf);   // all lanes, same addr -> 1 broadcast req
                        if (v < need) { __builtin_amdgcn_s_sleep(1); ++spin; } else top_seen = v;
                    }
                }
                // even wsc -> slot even -> slot+1 never wraps
                const short* hb = hring + rbh_top + slot * (16 * OO) + lr * OO;
#pragma unroll
                for (int kt = 0; kt < 4; ++kt) {
                    union { unsigned long long q[2]; short8 v; } w;
                    w.q[0] = aload64((const unsigned long long*)(hb + kt * 32 + lh * 8));
                    w.q[1] = aload64((const unsigned long long*)(hb + kt * 32 + lh * 8 + 4));
                    hTf[kt] = w.v;
                }
                const short* hb2 = hb + 16 * OO;
#pragma unroll
                for (int kt = 0; kt < 4; ++kt) {
                    union { unsigned long long q[2]; short8 v; } w;
                    w.q[0] = aload64((const unsigned long long*)(hb2 + kt * 32 + lh * 8));
                    w.q[1] = aload64((const unsigned long long*)(hb2 + kt * 32 + lh * 8 + 4));
                    hTfB[kt] = w.v;
                }
                const unsigned long long* cp =
                    (const unsigned long long*)(cring + rbc_top + slot * (OO * 16) + on * 16 + lh * 4);
                union { unsigned long long q; float f[2]; } c01, c23;
                c01.q = aload64(cp);
                c23.q = aload64(cp + 1);
                cT[0] = c01.f[0]; cT[1] = c01.f[1]; cT[2] = c23.f[0]; cT[3] = c23.f[1];
                const unsigned long long* cpB =
                    (const unsigned long long*)(cring + rbc_top + (slot + 1) * (OO * 16) + on * 16 + lh * 4);
                c01.q = aload64(cpB);
                c23.q = aload64(cpB + 1);
                cTB[0] = c01.f[0]; cTB[1] = c01.f[1]; cTB[2] = c23.f[0]; cTB[3] = c23.f[1];
            } else {
#pragma unroll
                for (int kt = 0; kt < 4; ++kt) hTf[kt] = hTfB[kt];
#pragma unroll
                for (int j = 0; j < 4; ++j) cT[j] = cTB[j];
            }
        } else {
#pragma unroll
            for (int kt = 0; kt < 4; ++kt) hTf[kt] = (short8)(short)0;
#pragma unroll
            for (int j = 0; j < 4; ++j) cT[j] = 0.f;
        }

        // ---------- MFMAs: x-proj + left first (independent of top loads), then top ----------
        f32x4 ax[4], accL[4], accT[4];
#pragma unroll
        for (int g = 0; g < 4; ++g)
            ax[g] = __builtin_amdgcn_mfma_f32_16x16x32_bf16(xf, wif_[g], zacc, 0, 0, 0);
#pragma unroll
        for (int g = 0; g < 4; ++g) {
            f32x4 a = ax[g];
#pragma unroll
            for (int kt = 0; kt < 4; ++kt)
                a = __builtin_amdgcn_mfma_f32_16x16x32_bf16(hLf[kt], whf[g][kt], a, 0, 0, 0);
            accL[g] = a;
        }

        // prefetch next column's x fragment (cached load; a full column to land)
        if (wsc + 1 < Ww) {
            const int wwN = fx ? (Ww - 2 - wsc) : (wsc + 1);
            if (lh < 2)
                xf_next = *(const short8*)(xT + ((hh * Ww + wwN) * BB + b0 + lr) * CC + lh * 8);
        }

#pragma unroll
        for (int g = 0; g < 4; ++g) {
            f32x4 a = ax[g];
#pragma unroll
            for (int kt = 0; kt < 4; ++kt)
                a = __builtin_amdgcn_mfma_f32_16x16x32_bf16(hTf[kt], whf[g][kt], a, 0, 0, 0);
            accT[g] = a;
        }

        // ---------- elementwise LSTM cell (D-layout: col=on, row b = lh*4+j) ----------
        float ctv[4];
        union { short sh[4]; unsigned long long q; } hpack;
#pragma unroll
        for (int j = 0; j < 4; ++j) {
            float iT = sigm(accT[0][j] + bi);
            float fT = sigm(accT[1][j] + bf_);
            float gT = tanh_(accT[2][j] + bg_);
            float oT = sigm(accT[3][j] + bo_);
            float c0 = fT * cT[j] + iT * gT;
            float h0 = oT * tanh_(c0);

            float iL = sigm(accL[0][j] + bi);
            float fL = sigm(accL[1][j] + bf_);
            float gL = tanh_(accL[2][j] + bg_);
            float oL = sigm(accL[3][j] + bo_);
            float c1 = fL * cL[j] + iL * gL;
            float h1 = oL * tanh_(c1);

            float ct = ws0 * c0 + ws1 * c1 + bb_;
            float ht = ws0 * h0 + ws1 * h1 + bb_;
            cL[j] = ct;
            ctv[j] = ct;
            hpack.sh[j] = f2bf(ht);
        }

        // deferred WAR barrier: protects the previous dump's stage reads (and drains its
        // nt stores) one full column late — hidden under this column's handshake+MFMA+cell.
        if ((wsc & 15) == 0 && wsc != 0) __syncthreads();

        // stage write: one 8B LDS write, swizzled column group
        {
            const int g_on = (on >> 3) & 15;
            *(unsigned long long*)&stage[on * 256 + ((wslot ^ g_on) << 4) + lh * 4] = hpack.q;
        }

        // ---------- back-pressure (even cols only; slack = depth-2 columns) ----------
        if (r < 31 && evenc && wsc >= depth) {
            const int need = wsc - (depth - 2);
            if (cons_seen < need) {
                int spin = 0;
                while (cons_seen < need && spin < SPIN_CAP) {
                    const int v = aloadI(consnext);
                    if (v < need) { __builtin_amdgcn_s_sleep(1); ++spin; } else cons_seen = v;
                }
            }
        }

        // ---------- ring publish straight from cell registers ----------
        if (r < 31) {
            // h: [b'][o] -> 4 scalar 2B stores (16-lane groups coalesce to 32B)
            short* hp = hring + rbh_me + slot * (16 * OO) + on;
#pragma unroll
            for (int j = 0; j < 4; ++j)
                astore16(hp + (lh * 4 + j) * OO, hpack.sh[j]);
            union { float f[2]; unsigned long long q; } p01, p23;
            p01.f[0] = ctv[0]; p01.f[1] = ctv[1];
            p23.f[0] = ctv[2]; p23.f[1] = ctv[3];
            unsigned long long* cp =
                (unsigned long long*)(cring + rbc_me + slot * (OO * 16) + on * 16 + lh * 4);
            astore64(cp, p01.q);
            astore64(cp + 1, p23.q);
        }

        __syncthreads();   // drains all waves' ring stores (vmcnt) + stage visibility

        // flag out IMMEDIATELY after the barrier, odd cols only (chunk boundary)
        if (!evenc && tid == 0) {
            if (r < 31) astoreI(myprog, wsc + 1);
            if (r > 0)  astoreI(mycons, wsc + 1);
        }

        // opportunistic non-blocking probe for next chunk's flag (hides one RTT under rebuild)
        if (r > 0 && !evenc && wsc < Ww - 1) {
            const int v = aloadI(topf);
            if (v > top_seen) top_seen = v;
        }

        // rebuild h_left A-frags from stage (conflict-free via wslot swizzle)
#pragma unroll
        for (int kt = 0; kt < 4; ++kt) {
            const int col = ((wslot ^ (kt * 4 + lh)) << 4) + lr;
            short8 f;
#pragma unroll
            for (int jj = 0; jj < 8; ++jj)
                f[jj] = stage[(kt * 32 + lh * 8 + jj) * 256 + col];
            hLf[kt] = f;
        }

        // output dump every 16 steps; NON-TEMPORAL stores (don't evict rings from L2).
        // No barrier here — the WAR barrier is deferred into the next column.
        if ((wsc & 15) == 15) {
            const int wbase = ww & ~15;
            const int q  = tid & 3;
            const int r0 = tid >> 2;
#pragma unroll
            for (int i = 0; i < 16; ++i) {
                const int row = r0 + (i << 7);
                const int o = row >> 4;
                const int b = row & 15;
                const int go = (o >> 3) & 15;
                f32x4 v;
#pragma unroll
                for (int k = 0; k < 4; ++k)
                    v[k] = bf2f(stage[o * 256 + (((q * 4 + k) ^ go) << 4) + b]);
                float* op = out + ((size_t)((d * OO + o) * BB + b0 + b)) * (Hh * Ww)
                                + hh * Ww + wbase + q * 4;
                __builtin_nontemporal_store(v, (f32x4*)op);
            }
        }
    }
}

extern "C" void kernel_launch(void* const* d_in, const int* in_sizes, int n_in,
                              void* d_out, int out_size, void* d_ws, size_t ws_size,
                              hipStream_t stream) {
    (void)in_sizes; (void)n_in; (void)out_size;

    const float* x     = (const float*)d_in[0];
    const float* w_ii  = (const float*)d_in[1];
    const float* w_hi  = (const float*)d_in[2];
    const float* b_i   = (const float*)d_in[3];
    const float* w_if  = (const float*)d_in[4];
    const float* w_hf  = (const float*)d_in[5];
    const float* b_f   = (const float*)d_in[6];
    const float* w_ig  = (const float*)d_in[7];
    const float* w_hg  = (const float*)d_in[8];
    const float* b_g   = (const float*)d_in[9];
    const float* w_io  = (const float*)d_in[10];
    const float* w_ho  = (const float*)d_in[11];
    const float* b_o   = (const float*)d_in[12];
    const float* wsum  = (const float*)d_in[13];
    const float* bias  = (const float*)d_in[14];
    float* outp        = (float*)d_out;

    char* ws = (char*)d_ws;
    int*   flags  = (int*)ws;                               // 16384 ints = 64 KB
    short* xTp    = (short*)(ws + (64u << 10));             // 4 MB
    const size_t off_h = (64u << 10) + (4u << 20);

    // adaptive ring depth: hring = depth MB, cring = 2*depth MB
    int depth = 8;
    const size_t need8 = off_h + ((size_t)8 << 20) + ((size_t)16 << 20) + (1u << 20);
    if (ws_size < need8) depth = 4;

    short* hringp = (short*)(ws + off_h);
    float* cringp = (float*)(ws + off_h + ((size_t)depth << 20));
    int*   progp  = flags;
    int*   consp  = flags + 256 * FSTRIDE;

    hipLaunchKernelGGL(mdlstm_init, dim3(8192), dim3(256), 0, stream, x, xTp, flags);

    mdlstm_main<<<dim3(256), dim3(512), 0, stream>>>(
        xTp,
        w_ii, w_hi, b_i,
        w_if, w_hf, b_f,
        w_ig, w_hg, b_g,
        w_io, w_ho, b_o,
        wsum, bias,
        hringp, cringp, progp, consp,
        outp, depth);
}

// Round 7
// 1027.179 us; speedup vs baseline: 1.2155x; 1.0621x over previous
//
#include <hip/hip_runtime.h>

#define Hh 32
#define Ww 128
#define BB 32
#define CC 16
#define OO 128
#define SPIN_CAP (1 << 23)
#define FSTRIDE 32    // 32 ints = 128B per flag: one cache line per flag, no false sharing

typedef __attribute__((ext_vector_type(8))) short short8;
typedef __attribute__((ext_vector_type(4))) float f32x4;

__device__ inline short f2bf(float f) {
    unsigned u = __builtin_bit_cast(unsigned, f);
    unsigned r = (u + 0x7FFFu + ((u >> 16) & 1u)) >> 16;
    return (short)r;
}
__device__ inline float bf2f(short s) {
    unsigned u = ((unsigned)(unsigned short)s) << 16;
    return __builtin_bit_cast(float, u);
}
__device__ inline float rcp_(float x) { return __builtin_amdgcn_rcpf(x); }
__device__ inline float sigm(float x) {
    return rcp_(1.f + __builtin_amdgcn_exp2f(-1.442695041f * x));
}
__device__ inline float tanh_(float x) {
    return 1.f - 2.f * rcp_(__builtin_amdgcn_exp2f(2.885390082f * x) + 1.f);
}

__device__ inline unsigned long long aload64(const unsigned long long* p) {
    return __hip_atomic_load(p, __ATOMIC_RELAXED, __HIP_MEMORY_SCOPE_AGENT);
}
__device__ inline void astore64(unsigned long long* p, unsigned long long v) {
    __hip_atomic_store(p, v, __ATOMIC_RELAXED, __HIP_MEMORY_SCOPE_AGENT);
}
__device__ inline void astore16(short* p, short v) {
    __hip_atomic_store(p, v, __ATOMIC_RELAXED, __HIP_MEMORY_SCOPE_AGENT);
}
__device__ inline int aloadI(const int* p) {
    return __hip_atomic_load(p, __ATOMIC_RELAXED, __HIP_MEMORY_SCOPE_AGENT);
}
__device__ inline void astoreI(int* p, int v) {
    __hip_atomic_store(p, v, __ATOMIC_RELAXED, __HIP_MEMORY_SCOPE_AGENT);
}

// ---- init: zero padded flags, transpose x (B,C,H,W) fp32 -> xT (H,W,B,C) bf16 ----
__global__ void mdlstm_init(const float* __restrict__ x, short* __restrict__ xT,
                            int* __restrict__ flags) {
    int idx = blockIdx.x * 256 + threadIdx.x;
    if (blockIdx.x < 64) flags[idx] = 0;   // 2 regions * 256 flags * FSTRIDE ints = 16384
    int w = idx & 127;
    int h = (idx >> 7) & 31;
    int c = (idx >> 12) & 15;
    int b = idx >> 16;
    float v = x[idx];
    xT[((h * Ww + w) * BB + b) * CC + c] = f2bf(v);
}

// ---- main persistent wavefront kernel: 256 blocks x 512 threads, 1 block/CU ----
__global__ void __launch_bounds__(512, 1) mdlstm_main(
    const short* __restrict__ xT,
    const float* __restrict__ w_ii, const float* __restrict__ w_hi, const float* __restrict__ b_i,
    const float* __restrict__ w_if, const float* __restrict__ w_hf, const float* __restrict__ b_f,
    const float* __restrict__ w_ig, const float* __restrict__ w_hg, const float* __restrict__ b_g,
    const float* __restrict__ w_io, const float* __restrict__ w_ho, const float* __restrict__ b_o,
    const float* __restrict__ wsum, const float* __restrict__ bias,
    short* __restrict__ hring, float* __restrict__ cring,
    int* __restrict__ prog, int* __restrict__ cons,
    float* __restrict__ out, int depth)
{
    const int chain = blockIdx.x & 7;       // d*2+s -> one XCD per chain
    const int r     = blockIdx.x >> 3;      // scan row 0..31
    const int d     = chain >> 1;
    const int s     = chain & 1;
    const int b0    = s * 16;
    const bool fy   = (d >= 2);
    const bool fx   = (d & 1);
    const int hh    = fy ? (Hh - 1 - r) : r;

    const int tid  = threadIdx.x;
    const int wv   = tid >> 6;    // 0..7
    const int lane = tid & 63;
    const int lr   = lane & 15;
    const int lh   = lane >> 4;
    const int on   = wv * 16 + lr;

    // stage: [w16][b16][o128] shorts, o-slot swizzled: element (w,b,o) at
    //   stage[(w&15)*2048 + b*128 + (((o>>3)^b)<<3) + (o&7)]
    // Rebuild = 4x ds_read_b128 at LDS minimum aliasing; writes 2-way max. 64 KB static.
    __shared__ short stage[16 * 16 * 128];

    // ---------- weight fragments (registers, loaded once) ----------
    const float* whp[4] = {w_hi, w_hf, w_hg, w_ho};
    const float* wip[4] = {w_ii, w_if, w_ig, w_io};
    short8 whf[4][4];
    short8 wif_[4];
#pragma unroll
    for (int g = 0; g < 4; ++g) {
#pragma unroll
        for (int kt = 0; kt < 4; ++kt) {
            const float* p = whp[g] + ((d * OO + on) * OO + kt * 32 + lh * 8);
            short8 f;
#pragma unroll
            for (int j = 0; j < 8; ++j) f[j] = f2bf(p[j]);
            whf[g][kt] = f;
        }
        short8 fi = (short8)(short)0;
        if (lh < 2) {
            const float* p = wip[g] + ((d * OO + on) * CC + lh * 8);
#pragma unroll
            for (int j = 0; j < 8; ++j) fi[j] = f2bf(p[j]);
        }
        wif_[g] = fi;
    }

    const float bi  = b_i[d * OO + on];
    const float bf_ = b_f[d * OO + on];
    const float bg_ = b_g[d * OO + on];
    const float bo_ = b_o[d * OO + on];
    const float bb_ = bias[d * OO + on];
    const float ws0 = wsum[d * 2 + 0];
    const float ws1 = wsum[d * 2 + 1];

    // flags: one 128B line each; value = columns complete (published at odd cols)
    int* topf      = prog + ((d * 32 + (r - 1)) * 2 + s) * FSTRIDE;
    int* myprog    = prog + ((d * 32 + r) * 2 + s) * FSTRIDE;
    int* mycons    = cons + ((d * 32 + r) * 2 + s) * FSTRIDE;
    int* consnext  = cons + ((d * 32 + (r + 1)) * 2 + s) * FSTRIDE;

    // ring layouts (s-split):
    //   hring: [(row*2+s)][slot][b':16][o:128] bf16
    //   cring: [(row*2+s)][slot][o:128][b':16] fp32
    const int rbh_me  = ((d * 32 + r)     * 2 + s) * depth * (16 * OO);
    const int rbh_top = ((d * 32 + (r-1)) * 2 + s) * depth * (16 * OO);
    const int rbc_me  = ((d * 32 + r)     * 2 + s) * depth * (OO * 16);
    const int rbc_top = ((d * 32 + (r-1)) * 2 + s) * depth * (OO * 16);
    const int smask   = depth - 1;

    short8 hLf[4];
#pragma unroll
    for (int kt = 0; kt < 4; ++kt) hLf[kt] = (short8)(short)0;
    float cL[4] = {0.f, 0.f, 0.f, 0.f};

    // T-branch results for the current pair (computed at even col)
    float c0A[4], h0A[4], c0B[4], h0B[4];
#pragma unroll
    for (int j = 0; j < 4; ++j) { c0A[j] = h0A[j] = c0B[j] = h0B[j] = 0.f; }
    f32x4 axB[4];   // x-proj of odd column, kept live through the even column

    int top_seen = 0, cons_seen = 0;
    const f32x4 zacc = {0.f, 0.f, 0.f, 0.f};

    // x fragments for current pair + prefetch for next pair
    short8 xfA = (short8)(short)0, xfB = (short8)(short)0;
    short8 xfN0 = (short8)(short)0, xfN1 = (short8)(short)0;
    if (lh < 2) {
        const int w0 = fx ? (Ww - 1) : 0;
        const int w1 = fx ? (Ww - 2) : 1;
        xfA = *(const short8*)(xT + ((hh * Ww + w0) * BB + b0 + lr) * CC + lh * 8);
        xfB = *(const short8*)(xT + ((hh * Ww + w1) * BB + b0 + lr) * CC + lh * 8);
    }

#pragma unroll 2
    for (int wsc = 0; wsc < Ww; ++wsc) {
        const int ww    = fx ? (Ww - 1 - wsc) : wsc;
        const int slot  = wsc & smask;
        const int wslot = ww & 15;
        const bool evenc = ((wsc & 1) == 0);

        // ================= even column: pair handshake + T-branch precompute ===========
        if (evenc) {
            short8 hTfA[4], hTfB[4];
            float cTA[4], cTB[4];
            if (r > 0) {
                const int need = wsc + 2;   // pair (wsc, wsc+1) published
                if (top_seen < need) {
                    int spin = 0;
                    while (top_seen < need && spin < SPIN_CAP) {
                        const int v = aloadI(topf);   // same addr all lanes -> broadcast
                        if (v < need) { __builtin_amdgcn_s_sleep(1); ++spin; } else top_seen = v;
                    }
                }
                // issue ALL pair loads now; ax MFMAs below cover their latency
                const short* hb = hring + rbh_top + slot * (16 * OO) + lr * OO;
                const short* hb2 = hb + 16 * OO;   // even slot -> slot+1 never wraps
#pragma unroll
                for (int kt = 0; kt < 4; ++kt) {
                    union { unsigned long long q[2]; short8 v; } w;
                    w.q[0] = aload64((const unsigned long long*)(hb + kt * 32 + lh * 8));
                    w.q[1] = aload64((const unsigned long long*)(hb + kt * 32 + lh * 8 + 4));
                    hTfA[kt] = w.v;
                }
#pragma unroll
                for (int kt = 0; kt < 4; ++kt) {
                    union { unsigned long long q[2]; short8 v; } w;
                    w.q[0] = aload64((const unsigned long long*)(hb2 + kt * 32 + lh * 8));
                    w.q[1] = aload64((const unsigned long long*)(hb2 + kt * 32 + lh * 8 + 4));
                    hTfB[kt] = w.v;
                }
                const unsigned long long* cp =
                    (const unsigned long long*)(cring + rbc_top + slot * (OO * 16) + on * 16 + lh * 4);
                union { unsigned long long q; float f[2]; } c01, c23;
                c01.q = aload64(cp);
                c23.q = aload64(cp + 1);
                cTA[0] = c01.f[0]; cTA[1] = c01.f[1]; cTA[2] = c23.f[0]; cTA[3] = c23.f[1];
                const unsigned long long* cpB =
                    (const unsigned long long*)(cring + rbc_top + (slot + 1) * (OO * 16) + on * 16 + lh * 4);
                c01.q = aload64(cpB);
                c23.q = aload64(cpB + 1);
                cTB[0] = c01.f[0]; cTB[1] = c01.f[1]; cTB[2] = c23.f[0]; cTB[3] = c23.f[1];
            } else {
#pragma unroll
                for (int kt = 0; kt < 4; ++kt) { hTfA[kt] = (short8)(short)0; hTfB[kt] = (short8)(short)0; }
#pragma unroll
                for (int j = 0; j < 4; ++j) { cTA[j] = 0.f; cTB[j] = 0.f; }
            }

            // x-proj for both columns (independent of top loads -> hides their latency)
            f32x4 axA[4];
#pragma unroll
            for (int g = 0; g < 4; ++g) {
                axA[g] = __builtin_amdgcn_mfma_f32_16x16x32_bf16(xfA, wif_[g], zacc, 0, 0, 0);
                axB[g] = __builtin_amdgcn_mfma_f32_16x16x32_bf16(xfB, wif_[g], zacc, 0, 0, 0);
            }

            // prefetch next pair's x fragments (L2-resident)
            if (lh < 2 && wsc + 3 < Ww + 1) {
                if (wsc + 2 < Ww) {
                    const int wN0 = fx ? (Ww - 3 - wsc) : (wsc + 2);
                    xfN0 = *(const short8*)(xT + ((hh * Ww + wN0) * BB + b0 + lr) * CC + lh * 8);
                }
                if (wsc + 3 < Ww) {
                    const int wN1 = fx ? (Ww - 4 - wsc) : (wsc + 3);
                    xfN1 = *(const short8*)(xT + ((hh * Ww + wN1) * BB + b0 + lr) * CC + lh * 8);
                }
            }

            // T-branch column A
            {
                f32x4 aT[4];
#pragma unroll
                for (int g = 0; g < 4; ++g) {
                    f32x4 a = axA[g];
#pragma unroll
                    for (int kt = 0; kt < 4; ++kt)
                        a = __builtin_amdgcn_mfma_f32_16x16x32_bf16(hTfA[kt], whf[g][kt], a, 0, 0, 0);
                    aT[g] = a;
                }
#pragma unroll
                for (int j = 0; j < 4; ++j) {
                    float iT = sigm(aT[0][j] + bi);
                    float fT = sigm(aT[1][j] + bf_);
                    float gT = tanh_(aT[2][j] + bg_);
                    float oT = sigm(aT[3][j] + bo_);
                    float c0 = fT * cTA[j] + iT * gT;
                    c0A[j] = c0;
                    h0A[j] = oT * tanh_(c0);
                }
            }
            // T-branch column B
            {
                f32x4 aT[4];
#pragma unroll
                for (int g = 0; g < 4; ++g) {
                    f32x4 a = axB[g];
#pragma unroll
                    for (int kt = 0; kt < 4; ++kt)
                        a = __builtin_amdgcn_mfma_f32_16x16x32_bf16(hTfB[kt], whf[g][kt], a, 0, 0, 0);
                    aT[g] = a;
                }
#pragma unroll
                for (int j = 0; j < 4; ++j) {
                    float iT = sigm(aT[0][j] + bi);
                    float fT = sigm(aT[1][j] + bf_);
                    float gT = tanh_(aT[2][j] + bg_);
                    float oT = sigm(aT[3][j] + bo_);
                    float c0 = fT * cTB[j] + iT * gT;
                    c0B[j] = c0;
                    h0B[j] = oT * tanh_(c0);
                }
            }
        }

        // ================= serial left-chain for this column ===========================
        f32x4 accL[4];
        {
            // start from this column's x-proj (axA transient at even col, axB kept at odd)
#pragma unroll
            for (int g = 0; g < 4; ++g) {
                f32x4 a = evenc
                    ? __builtin_amdgcn_mfma_f32_16x16x32_bf16(xfA, wif_[g], zacc, 0, 0, 0)
                    : axB[g];
#pragma unroll
                for (int kt = 0; kt < 4; ++kt)
                    a = __builtin_amdgcn_mfma_f32_16x16x32_bf16(hLf[kt], whf[g][kt], a, 0, 0, 0);
                accL[g] = a;
            }
        }

        float ctv[4];
        union { short sh[4]; unsigned long long q; } hpack;
#pragma unroll
        for (int j = 0; j < 4; ++j) {
            float iL = sigm(accL[0][j] + bi);
            float fL = sigm(accL[1][j] + bf_);
            float gL = tanh_(accL[2][j] + bg_);
            float oL = sigm(accL[3][j] + bo_);
            float c1 = fL * cL[j] + iL * gL;
            float h1 = oL * tanh_(c1);

            const float c0 = evenc ? c0A[j] : c0B[j];
            const float h0 = evenc ? h0A[j] : h0B[j];
            float ct = ws0 * c0 + ws1 * c1 + bb_;
            float ht = ws0 * h0 + ws1 * h1 + bb_;
            cL[j] = ct;
            ctv[j] = ct;
            hpack.sh[j] = f2bf(ht);
        }

        // deferred WAR barrier: protects the previous dump's stage reads, one col late
        if ((wsc & 15) == 0 && wsc != 0) __syncthreads();

        // stage write: 4x 2B, layout [w][b][o] with slot^b swizzle (2-way max aliasing)
#pragma unroll
        for (int j = 0; j < 4; ++j) {
            const int b = lh * 4 + j;
            stage[wslot * 2048 + b * 128 + ((((on >> 3) ^ b) << 3)) + (on & 7)] = hpack.sh[j];
        }

        // ---------- back-pressure (even cols only) ----------
        if (r < 31 && evenc && wsc >= depth) {
            const int need = wsc - (depth - 2);
            if (cons_seen < need) {
                int spin = 0;
                while (cons_seen < need && spin < SPIN_CAP) {
                    const int v = aloadI(consnext);
                    if (v < need) { __builtin_amdgcn_s_sleep(1); ++spin; } else cons_seen = v;
                }
            }
        }

        // ---------- ring publish straight from cell registers ----------
        if (r < 31) {
            short* hp = hring + rbh_me + slot * (16 * OO) + on;
#pragma unroll
            for (int j = 0; j < 4; ++j)
                astore16(hp + (lh * 4 + j) * OO, hpack.sh[j]);
            union { float f[2]; unsigned long long q; } p01, p23;
            p01.f[0] = ctv[0]; p01.f[1] = ctv[1];
            p23.f[0] = ctv[2]; p23.f[1] = ctv[3];
            unsigned long long* cp =
                (unsigned long long*)(cring + rbc_me + slot * (OO * 16) + on * 16 + lh * 4);
            astore64(cp, p01.q);
            astore64(cp + 1, p23.q);
        }

        __syncthreads();   // drains ring stores (vmcnt) + stage visibility

        // flag out IMMEDIATELY after the barrier, odd cols only (chunk boundary)
        if (!evenc && tid == 0) {
            if (r < 31) astoreI(myprog, wsc + 1);
            if (r > 0)  astoreI(mycons, wsc + 1);
        }

        // opportunistic probe for next chunk's flag (hides one RTT under rebuild)
        if (r > 0 && !evenc && wsc < Ww - 1) {
            const int v = aloadI(topf);
            if (v > top_seen) top_seen = v;
        }

        // rebuild h_left A-frags: 4x ds_read_b128 (swizzled, minimum-aliasing)
#pragma unroll
        for (int kt = 0; kt < 4; ++kt) {
            const int idx = wslot * 2048 + lr * 128 + ((((kt << 2) + lh) ^ lr) << 3);
            hLf[kt] = *(const short8*)&stage[idx];
        }

        // advance x pair registers at odd cols
        if (!evenc) { xfA = xfN0; xfB = xfN1; }

        // output dump every 16 steps; NON-TEMPORAL stores (don't evict rings from L2)
        if ((wsc & 15) == 15) {
            const int wbase = ww & ~15;
            const int q  = tid & 3;
            const int r0 = tid >> 2;
#pragma unroll
            for (int i = 0; i < 16; ++i) {
                const int row = r0 + (i << 7);
                const int o = row >> 4;
                const int b = row & 15;
                f32x4 v;
#pragma unroll
                for (int k = 0; k < 4; ++k)
                    v[k] = bf2f(stage[(q * 4 + k) * 2048 + b * 128
                                      + (((o >> 3) ^ b) << 3) + (o & 7)]);
                float* op = out + ((size_t)((d * OO + o) * BB + b0 + b)) * (Hh * Ww)
                                + hh * Ww + wbase + q * 4;
                __builtin_nontemporal_store(v, (f32x4*)op);
            }
        }
    }
}

extern "C" void kernel_launch(void* const* d_in, const int* in_sizes, int n_in,
                              void* d_out, int out_size, void* d_ws, size_t ws_size,
                              hipStream_t stream) {
    (void)in_sizes; (void)n_in; (void)out_size;

    const float* x     = (const float*)d_in[0];
    const float* w_ii  = (const float*)d_in[1];
    const float* w_hi  = (const float*)d_in[2];
    const float* b_i   = (const float*)d_in[3];
    const float* w_if  = (const float*)d_in[4];
    const float* w_hf  = (const float*)d_in[5];
    const float* b_f   = (const float*)d_in[6];
    const float* w_ig  = (const float*)d_in[7];
    const float* w_hg  = (const float*)d_in[8];
    const float* b_g   = (const float*)d_in[9];
    const float* w_io  = (const float*)d_in[10];
    const float* w_ho  = (const float*)d_in[11];
    const float* b_o   = (const float*)d_in[12];
    const float* wsum  = (const float*)d_in[13];
    const float* bias  = (const float*)d_in[14];
    float* outp        = (float*)d_out;

    char* ws = (char*)d_ws;
    int*   flags  = (int*)ws;                               // 16384 ints = 64 KB
    short* xTp    = (short*)(ws + (64u << 10));             // 4 MB
    const size_t off_h = (64u << 10) + (4u << 20);

    // adaptive ring depth: hring = depth MB, cring = 2*depth MB
    int depth = 8;
    const size_t need8 = off_h + ((size_t)8 << 20) + ((size_t)16 << 20) + (1u << 20);
    if (ws_size < need8) depth = 4;

    short* hringp = (short*)(ws + off_h);
    float* cringp = (float*)(ws + off_h + ((size_t)depth << 20));
    int*   progp  = flags;
    int*   consp  = flags + 256 * FSTRIDE;

    hipLaunchKernelGGL(mdlstm_init, dim3(8192), dim3(256), 0, stream, x, xTp, flags);

    mdlstm_main<<<dim3(256), dim3(512), 0, stream>>>(
        xTp,
        w_ii, w_hi, b_i,
        w_if, w_hf, b_f,
        w_ig, w_hg, b_g,
        w_io, w_ho, b_o,
        wsum, bias,
        hringp, cringp, progp, consp,
        outp, depth);
}